// Round 1
// baseline (444.652 us; speedup 1.0000x reference)
//
#include <hip/hip_runtime.h>

// WOQ int4-asym (tinygemm) linear: out[64,8192] = x @ dequant(w).T
// w int32 in [0,15]; dequant: (q - 8)*scale + zp, groups of 128 along K.
//
// R3: ZERO-WORKSPACE experiment. Theory: dur_us 390 = ~2x159us 1-GiB
// d_ws re-poison fills (top-5 rocprof rows) + ~60us of actual kernels.
// The gemm itself is a 256 MB weight stream => 41us HBM floor.
// This version uses NO d_ws / NO atomics / NO second kernel / NO memset:
//   grid = 256 blocks (1/CU), 512 thr = 8 waves = (mh 0..1) x (kh 0..3).
//   Each wave: rows mh*32..+32 (2 m-frags) x all 32 n-cols (2 n-frags)
//   over K-quarter kh*2048..+2048. No barrier in main loop -> no
//   vmcnt-drain stall; weight stream pipelines freely.
//   Epilogue: one __syncthreads, kh>0 waves dump acc to LDS (24 KB,
//   lane-contiguous f32x4 = conflict-free), kh=0 waves sum + store f32.
// A-frags come straight from global x (L2-resident, 512 MB aggregate:
// ~11 TB/s of the 34.5 TB/s L2 ceiling). Weight rows duplicated only
// across the mh-pair on the same CU -> L1-served, HBM reads stay 256 MB.

#define OUT_F 8192
#define IN_F  8192
#define M_TOK 64
#define GROUP 128
#define BN    32
#define KW    4                 // k-split across waves inside the block
#define KR    (IN_F / KW)       // 2048 k per wave

typedef short short8 __attribute__((ext_vector_type(8)));
typedef float f32x4  __attribute__((ext_vector_type(4)));
typedef int   int4v  __attribute__((ext_vector_type(4)));

// pack two fp32 -> two bf16 (round-half-up) in one int (lo in low 16)
__device__ __forceinline__ int pack_bf2(float lo, float hi) {
    unsigned ul = __float_as_uint(lo) + 0x8000u;
    unsigned uh = __float_as_uint(hi) + 0x8000u;
    return (int)((ul >> 16) | (uh & 0xFFFF0000u));
}

__global__ __launch_bounds__(512, 2)
void woq_gemm(const float* __restrict__ x,
              const int*   __restrict__ qw,
              const float* __restrict__ sz,
              float*       __restrict__ outp) {
    // cross-wave k-reduction buffer: slot = (kh-1)*2+mh (0..5), 4 frags, 64 lanes
    __shared__ f32x4 red[6 * 4 * 64];   // 24 KB

    const int t    = threadIdx.x;
    const int lane = t & 63;
    const int wv   = t >> 6;        // 0..7
    const int mh   = wv & 1;        // m half: rows mh*32 .. +32
    const int kh   = wv >> 1;       // k quarter
    const int n0   = blockIdx.x * BN;

    const int nlo  = lane & 15;
    const int quad = lane >> 4;
    const int kq8  = quad << 3;     // this lane's 8-elem k run inside a 32-k step

    const int n1 = n0 + nlo;        // n-frag 0 column
    const int n2 = n1 + 16;         // n-frag 1 column
    const int m0 = mh * 32;

    const float* xr0 = x  + (size_t)(m0 + nlo) * IN_F;   // a-frag mi=0 row
    const float* xr1 = xr0 + (size_t)16 * IN_F;          // a-frag mi=1 row
    const int*   qr1 = qw + (size_t)n1 * IN_F;
    const int*   qr2 = qw + (size_t)n2 * IN_F;

    f32x4 acc[2][2];
#pragma unroll
    for (int mi = 0; mi < 2; ++mi)
#pragma unroll
        for (int ni = 0; ni < 2; ++ni)
            acc[mi][ni] = (f32x4){0.f, 0.f, 0.f, 0.f};

    const int kbase = kh * KR;

    for (int g = 0; g < KR / GROUP; ++g) {   // 16 groups of 128
        const int kg = kbase + g * GROUP;
        const int gg = kg >> 7;              // global group index

        // per-group scale / (zp - 8*scale) for this lane's two n columns
        const float2 p1 = *(const float2*)(sz + ((size_t)gg * OUT_F + n1) * 2);
        const float2 p2 = *(const float2*)(sz + ((size_t)gg * OUT_F + n2) * 2);
        const float s1 = p1.x, c1 = fmaf(-8.f, p1.x, p1.y);
        const float s2 = p2.x, c2 = fmaf(-8.f, p2.x, p2.y);

#pragma unroll
        for (int ks = 0; ks < 4; ++ks) {
            const int k = kg + ks * 32 + kq8;   // lane's k position

            // --- weight stream (the HBM-critical loads) ---
            const int4 qa = *(const int4*)(qr1 + k);
            const int4 qb = *(const int4*)(qr1 + k + 4);
            const int4 qc = *(const int4*)(qr2 + k);
            const int4 qd = *(const int4*)(qr2 + k + 4);

            // --- A from global x (L2-resident) ---
            const float4 va0 = *(const float4*)(xr0 + k);
            const float4 va1 = *(const float4*)(xr0 + k + 4);
            const float4 vb0 = *(const float4*)(xr1 + k);
            const float4 vb1 = *(const float4*)(xr1 + k + 4);

            int4v ai0, ai1;
            ai0.x = pack_bf2(va0.x, va0.y);
            ai0.y = pack_bf2(va0.z, va0.w);
            ai0.z = pack_bf2(va1.x, va1.y);
            ai0.w = pack_bf2(va1.z, va1.w);
            ai1.x = pack_bf2(vb0.x, vb0.y);
            ai1.y = pack_bf2(vb0.z, vb0.w);
            ai1.z = pack_bf2(vb1.x, vb1.y);
            ai1.w = pack_bf2(vb1.z, vb1.w);
            const short8 a0 = __builtin_bit_cast(short8, ai0);
            const short8 a1 = __builtin_bit_cast(short8, ai1);

            // --- dequant B to bf16 (pair-packed) ---
            int4v b1i, b2i;
            b1i.x = pack_bf2(fmaf((float)qa.x, s1, c1), fmaf((float)qa.y, s1, c1));
            b1i.y = pack_bf2(fmaf((float)qa.z, s1, c1), fmaf((float)qa.w, s1, c1));
            b1i.z = pack_bf2(fmaf((float)qb.x, s1, c1), fmaf((float)qb.y, s1, c1));
            b1i.w = pack_bf2(fmaf((float)qb.z, s1, c1), fmaf((float)qb.w, s1, c1));
            b2i.x = pack_bf2(fmaf((float)qc.x, s2, c2), fmaf((float)qc.y, s2, c2));
            b2i.y = pack_bf2(fmaf((float)qc.z, s2, c2), fmaf((float)qc.w, s2, c2));
            b2i.z = pack_bf2(fmaf((float)qd.x, s2, c2), fmaf((float)qd.y, s2, c2));
            b2i.w = pack_bf2(fmaf((float)qd.z, s2, c2), fmaf((float)qd.w, s2, c2));
            const short8 b1 = __builtin_bit_cast(short8, b1i);
            const short8 b2 = __builtin_bit_cast(short8, b2i);

            acc[0][0] = __builtin_amdgcn_mfma_f32_16x16x32_bf16(a0, b1, acc[0][0], 0, 0, 0);
            acc[1][0] = __builtin_amdgcn_mfma_f32_16x16x32_bf16(a1, b1, acc[1][0], 0, 0, 0);
            acc[0][1] = __builtin_amdgcn_mfma_f32_16x16x32_bf16(a0, b2, acc[0][1], 0, 0, 0);
            acc[1][1] = __builtin_amdgcn_mfma_f32_16x16x32_bf16(a1, b2, acc[1][1], 0, 0, 0);
        }
    }

    // ---- epilogue: reduce the 4 k-quarters across waves via LDS ----
    if (kh > 0) {
        const int sb = ((kh - 1) * 2 + mh) * 4 * 64;
#pragma unroll
        for (int mi = 0; mi < 2; ++mi)
#pragma unroll
            for (int ni = 0; ni < 2; ++ni)
                red[sb + (mi * 2 + ni) * 64 + lane] = acc[mi][ni];
    }
    __syncthreads();
    if (kh == 0) {
#pragma unroll
        for (int p = 0; p < 3; ++p) {
            const int sb = (p * 2 + mh) * 4 * 64;
#pragma unroll
            for (int mi = 0; mi < 2; ++mi)
#pragma unroll
                for (int ni = 0; ni < 2; ++ni)
                    acc[mi][ni] += red[sb + (mi * 2 + ni) * 64 + lane];
        }
        // C/D layout: col = lane&15 (n), row = quad*4 + r (m within frag)
#pragma unroll
        for (int mi = 0; mi < 2; ++mi)
#pragma unroll
            for (int ni = 0; ni < 2; ++ni) {
                const int n = n0 + ni * 16 + nlo;
#pragma unroll
                for (int r = 0; r < 4; ++r) {
                    const int m = m0 + mi * 16 + quad * 4 + r;
                    outp[(size_t)m * OUT_F + n] = acc[mi][ni][r];
                }
            }
    }
}

extern "C" void kernel_launch(void* const* d_in, const int* in_sizes, int n_in,
                              void* d_out, int out_size, void* d_ws, size_t ws_size,
                              hipStream_t stream) {
    const float* x  = (const float*)d_in[0];
    const int*   qw = (const int*)d_in[1];
    const float* sz = (const float*)d_in[2];
    float* out = (float*)d_out;

    // No workspace, no memset, no reduce kernel, no atomics: one launch.
    woq_gemm<<<dim3(OUT_F / BN), 512, 0, stream>>>(x, qw, sz, out);
}